// Round 11
// baseline (170.653 us; speedup 1.0000x reference)
//
#include <hip/hip_runtime.h>
#include <math.h>

#define EPSF 1e-8f
#define LAM 20.0f
#define LAML2E 28.853900817779268f  // LAM * log2(e)

typedef short short8 __attribute__((ext_vector_type(8)));
typedef float f32x4 __attribute__((ext_vector_type(4)));
typedef float f32x2 __attribute__((ext_vector_type(2)));

__device__ __forceinline__ unsigned short f2bf(float x) {
  unsigned u = __float_as_uint(x);
  u += 0x7fffu + ((u >> 16) & 1u);
  return (unsigned short)(u >> 16);
}
__device__ __forceinline__ float bf2f(unsigned short h) {
  return __uint_as_float(((unsigned)h) << 16);
}
// packed f32x2 -> bf16x2 (RNE bit-trick, proven R0-R2/R4-R6).
// NOTE: the v_cvt_pk_bf16_f32 inline-asm version NaNs (R7 bisect) — retired.
__device__ __forceinline__ unsigned pk2bf(float a, float b) {
  return (unsigned)f2bf(a) | ((unsigned)f2bf(b) << 16);
}
// packed f32x2 -> bf16x2 TRUNCATING, single v_perm_b32 (compiler builtin, not
// asm). dst = {b[31:16], a[31:16]}. Used only for e-values (<=1 ulp vs RNE).
__device__ __forceinline__ unsigned pk2bf_t(float a, float b) {
  return __builtin_amdgcn_perm(__float_as_uint(b), __float_as_uint(a),
                               0x07060302u);
}
// leaky-ReLU(0.1), scalar and packed-pair forms (exact: max(v, 0.1v)).
__device__ __forceinline__ float lrelu(float v) { return fmaxf(v, 0.1f * v); }
__device__ __forceinline__ f32x2 lrelu2(f32x2 v) {
  return __builtin_elementwise_max(v, v * 0.1f);  // v_pk_mul_f32 + 2x v_max
}
__device__ __forceinline__ f32x2 fma2(f32x2 a, f32x2 b, f32x2 c) {
  return __builtin_elementwise_fma(a, b, c);      // v_pk_fma_f32
}
// 2^x via compiler intrinsic (scheduler-managed; NOT inline asm — R3/R7 lesson)
__device__ __forceinline__ float exp2v(float x) {
  return __builtin_amdgcn_exp2f(x);
}
__device__ __forceinline__ void gload_lds16(const void* g, void* l) {
  __builtin_amdgcn_global_load_lds(
      (const __attribute__((address_space(1))) void*)g,
      (__attribute__((address_space(3))) void*)l, 16, 0, 0);
}

// ---------------------------------------------------------------------------
// Kernel 1: row norms + bf16 normalized copies (+ zero the loss accumulators).
// ---------------------------------------------------------------------------
__global__ __launch_bounds__(256) void norm_convert(
    const float* __restrict__ im, const float* __restrict__ s,
    float* __restrict__ nim, float* __restrict__ ns,
    unsigned short* __restrict__ imn, unsigned short* __restrict__ sn,
    float* __restrict__ acc) {
  if (blockIdx.x == 0 && threadIdx.x < 4) acc[threadIdx.x] = 0.f;
  int row = blockIdx.x * 4 + (threadIdx.x >> 6);
  int lane = threadIdx.x & 63;
  const float* src;
  unsigned short* dst;
  float* ndst;
  if (row < 8192) {
    src = im + ((size_t)row << 9);
    dst = imn + ((size_t)row << 9);
    ndst = nim + row;
  } else {
    int r = row - 8192;
    src = s + ((size_t)r << 9);
    dst = sn + ((size_t)r << 9);
    ndst = ns + r;
  }
  float4 v0 = ((const float4*)src)[lane * 2];
  float4 v1 = ((const float4*)src)[lane * 2 + 1];
  float ss = 0.f;
  ss = fmaf(v0.x, v0.x, ss); ss = fmaf(v0.y, v0.y, ss);
  ss = fmaf(v0.z, v0.z, ss); ss = fmaf(v0.w, v0.w, ss);
  ss = fmaf(v1.x, v1.x, ss); ss = fmaf(v1.y, v1.y, ss);
  ss = fmaf(v1.z, v1.z, ss); ss = fmaf(v1.w, v1.w, ss);
#pragma unroll
  for (int o = 32; o; o >>= 1) ss += __shfl_xor(ss, o);
  float n = sqrtf(ss);
  if (lane == 0) *ndst = n;
  float ci = 1.0f / (n + EPSF);
  uint4 pv;
  pv.x = pk2bf(v0.x * ci, v0.y * ci);
  pv.y = pk2bf(v0.z * ci, v0.w * ci);
  pv.z = pk2bf(v1.x * ci, v1.y * ci);
  pv.w = pk2bf(v1.z * ci, v1.w * ci);
  ((uint4*)dst)[lane] = pv;
}

// ---------------------------------------------------------------------------
// Kernel 2: bf16 Gram matrices via MFMA (LDS-staged bodies), one launch.
// ---------------------------------------------------------------------------
template <int LS>
__device__ __forceinline__ void gram_body(const unsigned short* __restrict__ ctxn,
                                          unsigned short* __restrict__ Gbf,
                                          int c, char* sm) {
  constexpr int RW = (LS / 16) / 2;
  const int t = threadIdx.x;
  const int w = t >> 6, lane = t & 63, m16 = lane & 15, grp = lane >> 4;
  const int rT0 = (w & 1) * RW, cT0 = (w >> 1) * RW;
  const unsigned short* base = ctxn + ((size_t)c * LS << 9);
  f32x4 g[RW][RW];
#pragma unroll
  for (int ri = 0; ri < RW; ri++)
#pragma unroll
    for (int ci = 0; ci < RW; ci++) g[ri][ci] = {0.f, 0.f, 0.f, 0.f};

  for (int ch = 0; ch < 4; ch++) {
    __syncthreads();
    for (int idx = t; idx < LS * 16; idx += 256) {
      int row = idx >> 4, u = idx & 15;
      *(uint4*)(sm + row * 272 + u * 16) =
          ((const uint4*)(base + ((size_t)row << 9) + (ch << 7)))[u];
    }
    __syncthreads();
#pragma unroll
    for (int kk = 0; kk < 4; kk++) {
      short8 a[RW], b[RW];
#pragma unroll
      for (int ri = 0; ri < RW; ri++)
        a[ri] = *(const short8*)(sm + ((rT0 + ri) * 16 + m16) * 272 + kk * 64 + grp * 16);
#pragma unroll
      for (int ci = 0; ci < RW; ci++)
        b[ci] = *(const short8*)(sm + ((cT0 + ci) * 16 + m16) * 272 + kk * 64 + grp * 16);
#pragma unroll
      for (int ri = 0; ri < RW; ri++)
#pragma unroll
        for (int ci = 0; ci < RW; ci++)
          g[ri][ci] = __builtin_amdgcn_mfma_f32_16x16x32_bf16(a[ri], b[ci], g[ri][ci], 0, 0, 0);
    }
  }
#pragma unroll
  for (int ri = 0; ri < RW; ri++)
#pragma unroll
    for (int ci = 0; ci < RW; ci++)
#pragma unroll
      for (int r = 0; r < 4; r++) {
        int s = (rT0 + ri) * 16 + grp * 4 + r;
        int sp = (cT0 + ci) * 16 + m16;
        Gbf[(size_t)c * LS * LS + s * LS + sp] = f2bf(g[ri][ci][r]);
      }
}

__global__ __launch_bounds__(256, 2) void gram_all(
    const unsigned short* __restrict__ imn, const unsigned short* __restrict__ sn,
    unsigned short* __restrict__ Gim, unsigned short* __restrict__ Gs) {
  __shared__ __align__(16) char sm[64 * 272];
  if (blockIdx.x < 128) gram_body<64>(imn, Gim, blockIdx.x, sm);
  else gram_body<32>(sn, Gs, blockIdx.x - 128, sm);
}

// ---------------------------------------------------------------------------
// Kernel 3: PAIRED attention (R10 structure).
//   This round: packed-FP32 math (f32x2 -> v_pk_fma_f32/v_pk_mul_f32) in the
//   four S0-consuming loops; per-column rinv accumulation order preserved
//   bit-exactly; sev uses two parallel partial sums (<=1 ulp reorder).
// LDS: staging 32768 | S0 33792 (aliases) + P 1024 + E_T/psum 8192 @36864
//    + float scratch 8224 @45056 = 53280 B -> 3 blocks/CU.
// ---------------------------------------------------------------------------
__global__ __launch_bounds__(256, 3) void attn_pair(
    const unsigned short* __restrict__ imn, const unsigned short* __restrict__ sn,
    const unsigned short* __restrict__ Gim, const unsigned short* __restrict__ Gs,
    const float* __restrict__ nim, const float* __restrict__ ns,
    const float* __restrict__ im_m, const float* __restrict__ s_m,
    float* __restrict__ i2t, float* __restrict__ t2i) {
  constexpr int S0P = 264;
  constexpr int GOFF = 36864;        // E_T (t2i) / psum (i2t P3), 8 KB
  constexpr int FOFF = GOFF + 8192;  // 45056: float scratch
  constexpr int POFF = 33792;        // sev partials (above S0 end, below GOFF)
  __shared__ __align__(16) char sm[FOFF + 2056 * 4];
  float* F = (float*)(sm + FOFF);
  float* rinv_i = F;          // [4][128] (persistent, pre-scaled by LAM*log2e)
  float* cmv_i = F + 512;     // [128]    (persistent; transformed in place)
  float* cmmax_i = F + 640;   // [2]+pad
  float* rinv_t = F + 644;    // [2][128] (t2i) | alias: sumev_i [2][128]
  float* sevt = F + 900;      // [4][128] raw sev (t2i)
  float* wn2t = F + 1412;     // [4][128] raw wn2 (t2i)
  float* cmv_t = F + 1924;    // [128]
  float* cmmax_t = F + 2052;  // [4]
  float* sumev_i = F + 644;
  float* psum = (float*)(sm + GOFF);  // [4][128] (i2t P3; E_T dead by then)

  const int bq = blockIdx.x;  // caption block: 4 cap ctxs = 128 cap rows
  const int bc = blockIdx.y;  // image block:   2 img ctxs = 128 img rows
  const int t = threadIdx.x;
  const int w = t >> 6, lane = t & 63, m16 = lane & 15, grp = lane >> 4;
  auto soff = [](int n) { return n * S0P; };

  const unsigned short* aBase = imn + ((size_t)bc << 16);  // img rows (ctx for i2t)
  const unsigned short* bBase = sn + ((size_t)bq << 16);   // cap rows (qry for i2t)

  // ---- preload masks, G_im fragments -> registers ----
  if (t < 128) cmv_i[t] = im_m[bc * 128 + t];
  else cmv_t[t - 128] = s_m[bq * 128 + (t - 128)];
  const int c3 = w >> 1, hf = w & 1;  // i2t P3: WPC=2
  short8 g_a[2][2];
  {
    const unsigned short* gB = Gim + ((size_t)bc * 2 + c3) * 4096;
#pragma unroll
    for (int mi = 0; mi < 2; mi++) {
      int sp = (hf * 2 + mi) * 16 + m16;
#pragma unroll
      for (int ks = 0; ks < 2; ks++)
        g_a[mi][ks] = *(const short8*)(gB + sp * 64 + ks * 32 + grp * 8);
    }
  }

  f32x4 regs[16];
#pragma unroll
  for (int i = 0; i < 16; i++) regs[i] = {0.f, 0.f, 0.f, 0.f};

  // ---- Phase 1: 128x128x512 score GEMM (global_load_lds staging) ----
  const int sT0 = (w & 1) * 4, nT0 = (w >> 1) * 4;
  const int r_lane = lane >> 3, c_lane = lane & 7;
  const unsigned short* wbase = (w < 2) ? (aBase + ((size_t)(w * 64) << 9))
                                        : (bBase + ((size_t)((w - 2) * 64) << 9));
  const unsigned short* pb = wbase + r_lane * 512 + ((c_lane ^ r_lane) << 3);
  char* ldsw = sm + w * 8192;
  const int sx = m16 & 7;
  for (int ch = 0; ch < 8; ch++) {
    __syncthreads();
#pragma unroll
    for (int j = 0; j < 8; j++)
      gload_lds16(pb + ch * 64 + j * 4096, ldsw + j * 1024);
    __syncthreads();
#pragma unroll
    for (int kk = 0; kk < 2; kk++) {
      short8 av[4], bv[4];
#pragma unroll
      for (int si = 0; si < 4; si++)
        av[si] = *(const short8*)(sm + (((sT0 + si) * 16 + m16) << 7) +
                                  (((kk * 4 + grp) ^ sx) << 4));
#pragma unroll
      for (int ni = 0; ni < 4; ni++)
        bv[ni] = *(const short8*)(sm + ((128 + (nT0 + ni) * 16 + m16) << 7) +
                                  (((kk * 4 + grp) ^ sx) << 4));
#pragma unroll
      for (int si = 0; si < 4; si++)
#pragma unroll
        for (int ni = 0; ni < 4; ni++)
          regs[si * 4 + ni] = __builtin_amdgcn_mfma_f32_16x16x32_bf16(
              av[si], bv[ni], regs[si * 4 + ni], 0, 0, 0);
    }
  }
  __syncthreads();
  // S0 bf16 [n=cap][m=img]
#pragma unroll
  for (int si = 0; si < 4; si++)
#pragma unroll
    for (int ni = 0; ni < 4; ni++) {
      int n = (nT0 + ni) * 16 + m16;
      int m0 = (sT0 + si) * 16 + grp * 4;
      f32x4 a = regs[si * 4 + ni];
      uint2 p;
      p.x = pk2bf(a[0], a[1]);
      p.y = pk2bf(a[2], a[3]);
      *(uint2*)(sm + soff(n) + m0 * 2) = p;
    }
  __syncthreads();

  // ---- rinv stage: i2t rinv (threads 0..127), t2i rinv (threads 128..255),
  //      cmmax by threads 0..5. rinv stored pre-scaled by LAM*log2e. ----
  if (t < 128) {
    if (t < 2) {
      float mx = cmv_i[t * 64];
      for (int s = 1; s < 64; s++) mx = fmaxf(mx, cmv_i[t * 64 + s]);
      cmmax_i[t] = mx;
    } else if (t < 6) {
      int ci = t - 2;
      float mx = cmv_t[ci * 32];
      for (int s = 1; s < 32; s++) mx = fmaxf(mx, cmv_t[ci * 32 + s]);
      cmmax_t[ci] = mx;
    }
    int qi = t >> 5, mg = (t & 31) * 4;
    f32x2 sa = {0.f, 0.f}, sb = {0.f, 0.f};
#pragma unroll 8
    for (int l = 0; l < 32; l++) {
      uint2 pk = *(const uint2*)(sm + soff(qi * 32 + l) + mg * 2);
      f32x2 v01 = {__uint_as_float(pk.x << 16),
                   __uint_as_float(pk.x & 0xffff0000u)};
      f32x2 v23 = {__uint_as_float(pk.y << 16),
                   __uint_as_float(pk.y & 0xffff0000u)};
      f32x2 l01 = lrelu2(v01), l23 = lrelu2(v23);
      sa = fma2(l01, l01, sa);
      sb = fma2(l23, l23, sb);
    }
    rinv_i[qi * 128 + mg + 0] = LAML2E / (sqrtf(sa.x) + EPSF);
    rinv_i[qi * 128 + mg + 1] = LAML2E / (sqrtf(sa.y) + EPSF);
    rinv_i[qi * 128 + mg + 2] = LAML2E / (sqrtf(sb.x) + EPSF);
    rinv_i[qi * 128 + mg + 3] = LAML2E / (sqrtf(sb.y) + EPSF);
  } else {
    int n = t - 128;  // cap row
#pragma unroll
    for (int qi = 0; qi < 2; qi++) {
      f32x2 ssa = {0.f, 0.f}, ssb = {0.f, 0.f};
#pragma unroll 4
      for (int j = 0; j < 16; j++) {
        uint2 pk = *(const uint2*)(sm + soff(n) + qi * 128 + j * 8);
        f32x2 v01 = {__uint_as_float(pk.x << 16),
                     __uint_as_float(pk.x & 0xffff0000u)};
        f32x2 v23 = {__uint_as_float(pk.y << 16),
                     __uint_as_float(pk.y & 0xffff0000u)};
        f32x2 l01 = lrelu2(v01), l23 = lrelu2(v23);
        ssa = fma2(l01, l01, ssa);
        ssb = fma2(l23, l23, ssb);
      }
      float ss = (ssa.x + ssa.y) + (ssb.x + ssb.y);
      rinv_t[qi * 128 + n] = LAML2E / (sqrtf(ss) + EPSF);
    }
  }
  __syncthreads();

  // ---- fold masks: cmv <- K*(cmv - 1 - cmmax), K=LAM*log2e
  //      (e = exp2(fma(l,rv,cv))) ----
  if (t < 128) cmv_i[t] = (cmv_i[t] - 1.0f - cmmax_i[t >> 6]) * LAML2E;
  else {
    int n2 = t - 128;
    cmv_t[n2] = (cmv_t[n2] - 1.0f - cmmax_t[n2 >> 5]) * LAML2E;
  }
  __syncthreads();

  // ---- t2i MFMA pass: per cap ctx ci (4 reps):
  //      e (16/thread) -> E_T bf16 [128 mp][32 s] (chunk-XOR-swizzled);
  //      U = G_s@E via MFMA; wn2 = sum_s e*U. All raw (inv cancels). ----
  {
    const int mp = t & 127;  // img col
    const int h = t >> 7;    // s-half
    const int qi = mp >> 6;
    char* ET = sm + GOFF;
    float* P = (float*)(sm + POFF);  // [256] sev partials
    const unsigned short* gB2 = Gs + ((size_t)bq << 12);
    const int esw = (mp >> 1) & 3;   // write-side chunk swizzle
    const int rsw = (m16 >> 1) & 3;  // read-side chunk swizzle
    for (int ci = 0; ci < 4; ci++) {
      // G_s A-fragments for this ctx (direct global loads, L1-hot after rep 0)
      short8 ga0 = *(const short8*)(gB2 + ci * 1024 + m16 * 32 + grp * 8);
      short8 ga1 = *(const short8*)(gB2 + ci * 1024 + (16 + m16) * 32 + grp * 8);
      const float* rv = rinv_t + qi * 128 + ci * 32 + h * 16;
      const float* cv = cmv_t + ci * 32 + h * 16;
      f32x2 sev2 = {0.f, 0.f};
      unsigned pk[8];
#pragma unroll
      for (int q = 0; q < 4; q++) {
        float4 r4 = *(const float4*)(rv + q * 4);
        float4 c4 = *(const float4*)(cv + q * 4);
        int s0 = ci * 32 + h * 16 + q * 4;
        float v0 = bf2f(*(const unsigned short*)(sm + soff(s0 + 0) + mp * 2));
        float v1 = bf2f(*(const unsigned short*)(sm + soff(s0 + 1) + mp * 2));
        float v2 = bf2f(*(const unsigned short*)(sm + soff(s0 + 2) + mp * 2));
        float v3 = bf2f(*(const unsigned short*)(sm + soff(s0 + 3) + mp * 2));
        f32x2 v01 = {v0, v1}, v23 = {v2, v3};
        f32x2 a01 = fma2(lrelu2(v01), (f32x2){r4.x, r4.y}, (f32x2){c4.x, c4.y});
        f32x2 a23 = fma2(lrelu2(v23), (f32x2){r4.z, r4.w}, (f32x2){c4.z, c4.w});
        float e0 = exp2v(a01.x), e1 = exp2v(a01.y);
        float e2 = exp2v(a23.x), e3 = exp2v(a23.y);
        sev2 = fma2((f32x2){e0, e1}, v01, sev2);
        sev2 = fma2((f32x2){e2, e3}, v23, sev2);
        pk[q * 2] = pk2bf_t(e0, e1);
        pk[q * 2 + 1] = pk2bf_t(e2, e3);
      }
      P[t] = sev2.x + sev2.y;
      uint4 w0; w0.x = pk[0]; w0.y = pk[1]; w0.z = pk[2]; w0.w = pk[3];
      uint4 w1; w1.x = pk[4]; w1.y = pk[5]; w1.z = pk[6]; w1.w = pk[7];
      char* rowp = ET + mp * 64;
      *(uint4*)(rowp + (((2 * h) ^ esw) << 4)) = w0;
      *(uint4*)(rowp + (((2 * h + 1) ^ esw) << 4)) = w1;
      __syncthreads();
      if (t < 128) sevt[ci * 128 + t] = P[t] + P[t + 128];
      // MFMA: wave w owns n-tiles {2w, 2w+1} (img cols 32w..32w+31)
      short8 bfrag[2];
#pragma unroll
      for (int nt = 0; nt < 2; nt++)
        bfrag[nt] = *(const short8*)(ET + (((w * 2 + nt) * 16 + m16) << 6) +
                                     ((grp ^ rsw) << 4));
      f32x4 u00 = __builtin_amdgcn_mfma_f32_16x16x32_bf16(ga0, bfrag[0], (f32x4){0.f, 0.f, 0.f, 0.f}, 0, 0, 0);
      f32x4 u01 = __builtin_amdgcn_mfma_f32_16x16x32_bf16(ga0, bfrag[1], (f32x4){0.f, 0.f, 0.f, 0.f}, 0, 0, 0);
      f32x4 u10 = __builtin_amdgcn_mfma_f32_16x16x32_bf16(ga1, bfrag[0], (f32x4){0.f, 0.f, 0.f, 0.f}, 0, 0, 0);
      f32x4 u11 = __builtin_amdgcn_mfma_f32_16x16x32_bf16(ga1, bfrag[1], (f32x4){0.f, 0.f, 0.f, 0.f}, 0, 0, 0);
#pragma unroll
      for (int nt = 0; nt < 2; nt++) {
        const char* erow = ET + (((w * 2 + nt) * 16 + m16) << 6);
        float part = 0.f;
#pragma unroll
        for (int mt = 0; mt < 2; mt++) {
          int cch = 2 * mt + (grp >> 1);
          uint2 ee = *(const uint2*)(erow + ((cch ^ rsw) << 4) + ((grp & 1) << 3));
          f32x4 uu = (mt == 0) ? (nt == 0 ? u00 : u01) : (nt == 0 ? u10 : u11);
          part += __uint_as_float(ee.x << 16) * uu[0];
          part += __uint_as_float(ee.x & 0xffff0000u) * uu[1];
          part += __uint_as_float(ee.y << 16) * uu[2];
          part += __uint_as_float(ee.y & 0xffff0000u) * uu[3];
        }
        part += __shfl_xor(part, 16);
        part += __shfl_xor(part, 32);
        if (lane < 16) wn2t[ci * 128 + (w * 2 + nt) * 16 + m16] = part;
      }
      __syncthreads();
    }
  }

  // ---- t2i final: cos + mean over 64 img words (inv-cancelled form) ----
  {
    const int p = t >> 5, l0 = t & 31;
    const int cc = p >> 1, qi = p & 1;
    float sum = 0.f;
#pragma unroll
    for (int li = 0; li < 2; li++) {
      int n = qi * 64 + l0 + li * 32;
      float nq = nim[bc * 128 + n];
      float sev = sevt[cc * 128 + n];
      float wn2 = wn2t[cc * 128 + n];
      float denom = fmaxf(nq * sqrtf(fmaxf(wn2, 0.f)), 1e-30f);
      sum += (nq + EPSF) * sev / denom;
    }
#pragma unroll
    for (int o = 1; o < 32; o <<= 1) sum += __shfl_xor(sum, o);
    if (l0 == 0) t2i[(bq * 4 + cc) * 128 + bc * 2 + qi] = sum * (1.0f / 64.f);
  }
  __syncthreads();  // rinv_t region dies; sumev_i aliases it

  // ---- i2t 2b: one-pass e in place (sum/inv dropped — cancels in final) ----
  {
    const int n = t & 127;
    const int qi = n >> 5;
    const int ci = t >> 7;  // GC=2, one ci per thread
    char* rowp = sm + soff(n) + ci * 128;
    const float* rv = rinv_i + qi * 128 + ci * 64;
    const float* cv = cmv_i + ci * 64;
    f32x2 sev2 = {0.f, 0.f};
#pragma unroll
    for (int u = 0; u < 16; u++) {
      uint2 pk = *(const uint2*)(rowp + u * 8);
      float4 rv4 = *(const float4*)(rv + u * 4);
      float4 cv4 = *(const float4*)(cv + u * 4);
      f32x2 v01 = {__uint_as_float(pk.x << 16),
                   __uint_as_float(pk.x & 0xffff0000u)};
      f32x2 v23 = {__uint_as_float(pk.y << 16),
                   __uint_as_float(pk.y & 0xffff0000u)};
      f32x2 a01 = fma2(lrelu2(v01), (f32x2){rv4.x, rv4.y}, (f32x2){cv4.x, cv4.y});
      f32x2 a23 = fma2(lrelu2(v23), (f32x2){rv4.z, rv4.w}, (f32x2){cv4.z, cv4.w});
      float e0 = exp2v(a01.x), e1 = exp2v(a01.y);
      float e2 = exp2v(a23.x), e3 = exp2v(a23.y);
      sev2 = fma2((f32x2){e0, e1}, v01, sev2);
      sev2 = fma2((f32x2){e2, e3}, v23, sev2);
      uint2 o;
      o.x = pk2bf_t(e0, e1);
      o.y = pk2bf_t(e2, e3);
      *(uint2*)(rowp + u * 8) = o;
    }
    sumev_i[ci * 128 + n] = sev2.x + sev2.y;
  }
  __syncthreads();

  // ---- i2t P3: U = G_im @ e (MFMA, A from regs); wn2 from C-regs ----
  {
#pragma unroll
    for (int i = 0; i < 16; i++) regs[i] = {0.f, 0.f, 0.f, 0.f};
#pragma unroll
    for (int ks = 0; ks < 2; ks++) {
      short8 b2[8];
#pragma unroll
      for (int nt = 0; nt < 8; nt++) {
        const char* p = sm + soff(nt * 16 + m16) + c3 * 128 + ks * 64 + grp * 16;
        union { uint2 h[2]; short8 v; } bb;
        bb.h[0] = *(const uint2*)(p);
        bb.h[1] = *(const uint2*)(p + 8);
        b2[nt] = bb.v;
      }
#pragma unroll
      for (int mi = 0; mi < 2; mi++)
#pragma unroll
        for (int nt = 0; nt < 8; nt++)
          regs[mi * 8 + nt] = __builtin_amdgcn_mfma_f32_16x16x32_bf16(
              g_a[mi][ks], b2[nt], regs[mi * 8 + nt], 0, 0, 0);
    }
    float wp[8];
#pragma unroll
    for (int nt = 0; nt < 8; nt++) wp[nt] = 0.f;
#pragma unroll
    for (int nt = 0; nt < 8; nt++) {
#pragma unroll
      for (int mi = 0; mi < 2; mi++) {
        int sp = (hf * 2 + mi) * 16 + grp * 4;
        uint2 ee = *(const uint2*)(sm + soff(nt * 16 + m16) + (c3 * 64 + sp) * 2);
        f32x4 uu = regs[mi * 8 + nt];
        wp[nt] += __uint_as_float(ee.x << 16) * uu[0] +
                  __uint_as_float(ee.x & 0xffff0000u) * uu[1] +
                  __uint_as_float(ee.y << 16) * uu[2] +
                  __uint_as_float(ee.y & 0xffff0000u) * uu[3];
      }
    }
#pragma unroll
    for (int o = 16; o < 64; o <<= 1)
#pragma unroll
      for (int nt = 0; nt < 8; nt++) wp[nt] += __shfl_xor(wp[nt], o);
    if (lane < 16) {
#pragma unroll
      for (int nt = 0; nt < 8; nt++) psum[w * 128 + nt * 16 + lane] = wp[nt];
    }
  }
  __syncthreads();

  // ---- i2t final: cos + mean over 32 cap words (inv-cancelled form) ----
  {
    const int p = t >> 5, l0 = t & 31;
    const int cc = p >> 2, qi = p & 3;
    int n = qi * 32 + l0;
    float nq = ns[bq * 128 + n];
    float sev = sumev_i[cc * 128 + n];
    float wn2u = psum[(cc * 2 + 0) * 128 + n] + psum[(cc * 2 + 1) * 128 + n];
    float denom = fmaxf(nq * sqrtf(fmaxf(wn2u, 0.f)), 1e-30f);
    float sum = (nq + EPSF) * sev / denom;
#pragma unroll
    for (int o = 1; o < 32; o <<= 1) sum += __shfl_xor(sum, o);
    if (l0 == 0) i2t[(bc * 2 + cc) * 128 + bq * 4 + qi] = sum * (1.0f / 32.f);
  }
}

// ---------------------------------------------------------------------------
// Kernel 4: fused loss (R11-proven).
// ---------------------------------------------------------------------------
__global__ __launch_bounds__(128) void loss_fused(
    const float* __restrict__ gsim, const float* __restrict__ i2t,
    const float* __restrict__ t2i, float* __restrict__ acc,
    float* __restrict__ out) {
  const int i = blockIdx.x, j = threadIdx.x;
  const int B = 128;
  __shared__ float sh[2];
  auto bmax = [&](float v) -> float {
#pragma unroll
    for (int o = 32; o; o >>= 1) v = fmaxf(v, __shfl_down(v, o));
    if ((j & 63) == 0) sh[j >> 6] = v;
    __syncthreads();
    float r = fmaxf(sh[0], sh[1]);
    __syncthreads();
    return r;
  };
  auto bsum = [&](float v) -> float {
#pragma unroll
    for (int o = 32; o; o >>= 1) v += __shfl_down(v, o);
    if ((j & 63) == 0) sh[j >> 6] = v;
    __syncthreads();
    float r = sh[0] + sh[1];
    __syncthreads();
    return r;
  };
  float xr = gsim[i * B + j] * 20.f;
  float xc = gsim[j * B + i] * 20.f;
  float sc = (i2t[i * B + j] + t2i[j * B + i]) * LAM;
  float mr = bmax(xr);
  float lser = mr + logf(bsum(__expf(xr - mr)));
  float mc = bmax(xc);
  float lsec = mc + logf(bsum(__expf(xc - mc)));
  float ml = bmax(sc);
  float lsel = ml + logf(bsum(__expf(sc - ml)));
  float pred = __expf(sc - lsel);
  float logLab = (i == j) ? logf(1.0f + 1e-6f) : logf(1e-6f);
  float tsum = bsum(pred * (sc - lsel - logLab));
  if (j == 0) {
    float d = gsim[i * B + i] * 20.f;
    atomicAdd(&acc[0], d - lser);
    atomicAdd(&acc[1], d - lsec);
    atomicAdd(&acc[2], tsum);
    __threadfence();
    unsigned old = atomicAdd((unsigned*)&acc[3], 1u);
    if (old == 127u) {
      __threadfence();
      float a = acc[0], b = acc[1], c = acc[2];
      float gl = -(a / 128.f) - (b / 128.f);
      float ll = c / 128.f;
      out[0] = gl + ll;
      out[1] = gl;
      out[2] = ll;
    }
  }
}

extern "C" void kernel_launch(void* const* d_in, const int* in_sizes, int n_in,
                              void* d_out, int out_size, void* d_ws,
                              size_t ws_size, hipStream_t stream) {
  const float* gsim = (const float*)d_in[0];  // (128,128)
  const float* im = (const float*)d_in[1];    // (128,64,512)
  const float* s = (const float*)d_in[2];     // (128,32,512)
  const float* im_m = (const float*)d_in[3];  // (128,64)
  const float* s_m = (const float*)d_in[5];   // (128,32)
  float* out = (float*)d_out;

  float* ws = (float*)d_ws;
  float* nim = ws;                                         // 8192
  float* ns = ws + 8192;                                   // 4096
  float* i2t = ws + 12288;                                 // 16384
  float* t2i = ws + 28672;                                 // 16384
  float* acc = ws + 45056;                                 // 4
  unsigned short* Gim = (unsigned short*)(ws + 45440);     // 128*64*64 bf16
  unsigned short* Gs = (unsigned short*)(ws + 307584);     // 128*32*32 bf16
  unsigned short* imn = (unsigned short*)(ws + 373120);    // 128*64*512 bf16
  unsigned short* sn = (unsigned short*)(ws + 2470272);    // 128*32*512 bf16

  norm_convert<<<dim3(3072), dim3(256), 0, stream>>>(im, s, nim, ns, imn, sn, acc);
  gram_all<<<dim3(256), dim3(256), 0, stream>>>(imn, sn, Gim, Gs);
  attn_pair<<<dim3(32, 64), dim3(256), 0, stream>>>(imn, sn, Gim, Gs, nim, ns,
                                                    im_m, s_m, i2t, t2i);
  loss_fused<<<dim3(128), dim3(128), 0, stream>>>(gsim, i2t, t2i, acc, out);
}

// Round 12
// 167.590 us; speedup vs baseline: 1.0183x; 1.0183x over previous
//
#include <hip/hip_runtime.h>
#include <math.h>

#define EPSF 1e-8f
#define LAM 20.0f
#define LAML2E 28.853900817779268f  // LAM * log2(e)

typedef short short8 __attribute__((ext_vector_type(8)));
typedef float f32x4 __attribute__((ext_vector_type(4)));
typedef float f32x2 __attribute__((ext_vector_type(2)));

__device__ __forceinline__ unsigned short f2bf(float x) {
  unsigned u = __float_as_uint(x);
  u += 0x7fffu + ((u >> 16) & 1u);
  return (unsigned short)(u >> 16);
}
__device__ __forceinline__ float bf2f(unsigned short h) {
  return __uint_as_float(((unsigned)h) << 16);
}
// packed f32x2 -> bf16x2 (RNE bit-trick, proven R0-R2/R4-R6).
// NOTE: the v_cvt_pk_bf16_f32 inline-asm version NaNs (R7 bisect) — retired.
__device__ __forceinline__ unsigned pk2bf(float a, float b) {
  return (unsigned)f2bf(a) | ((unsigned)f2bf(b) << 16);
}
// packed f32x2 -> bf16x2 TRUNCATING, single v_perm_b32 (compiler builtin, not
// asm). dst = {b[31:16], a[31:16]}. Used only for e-values (<=1 ulp vs RNE).
__device__ __forceinline__ unsigned pk2bf_t(float a, float b) {
  return __builtin_amdgcn_perm(__float_as_uint(b), __float_as_uint(a),
                               0x07060302u);
}
// leaky-ReLU(0.1), scalar and packed-pair forms (exact: max(v, 0.1v)).
__device__ __forceinline__ float lrelu(float v) { return fmaxf(v, 0.1f * v); }
__device__ __forceinline__ f32x2 lrelu2(f32x2 v) {
  return __builtin_elementwise_max(v, v * 0.1f);  // v_pk_mul_f32 + 2x v_max
}
__device__ __forceinline__ f32x2 fma2(f32x2 a, f32x2 b, f32x2 c) {
  return __builtin_elementwise_fma(a, b, c);      // v_pk_fma_f32
}
// 2^x via compiler intrinsic (scheduler-managed; NOT inline asm — R3/R7 lesson)
__device__ __forceinline__ float exp2v(float x) {
  return __builtin_amdgcn_exp2f(x);
}
__device__ __forceinline__ void gload_lds16(const void* g, void* l) {
  __builtin_amdgcn_global_load_lds(
      (const __attribute__((address_space(1))) void*)g,
      (__attribute__((address_space(3))) void*)l, 16, 0, 0);
}

// ---------------------------------------------------------------------------
// Kernel 1: row norms + bf16 normalized copies (+ zero the loss accumulators).
// ---------------------------------------------------------------------------
__global__ __launch_bounds__(256) void norm_convert(
    const float* __restrict__ im, const float* __restrict__ s,
    float* __restrict__ nim, float* __restrict__ ns,
    unsigned short* __restrict__ imn, unsigned short* __restrict__ sn,
    float* __restrict__ acc) {
  if (blockIdx.x == 0 && threadIdx.x < 4) acc[threadIdx.x] = 0.f;
  int row = blockIdx.x * 4 + (threadIdx.x >> 6);
  int lane = threadIdx.x & 63;
  const float* src;
  unsigned short* dst;
  float* ndst;
  if (row < 8192) {
    src = im + ((size_t)row << 9);
    dst = imn + ((size_t)row << 9);
    ndst = nim + row;
  } else {
    int r = row - 8192;
    src = s + ((size_t)r << 9);
    dst = sn + ((size_t)r << 9);
    ndst = ns + r;
  }
  float4 v0 = ((const float4*)src)[lane * 2];
  float4 v1 = ((const float4*)src)[lane * 2 + 1];
  float ss = 0.f;
  ss = fmaf(v0.x, v0.x, ss); ss = fmaf(v0.y, v0.y, ss);
  ss = fmaf(v0.z, v0.z, ss); ss = fmaf(v0.w, v0.w, ss);
  ss = fmaf(v1.x, v1.x, ss); ss = fmaf(v1.y, v1.y, ss);
  ss = fmaf(v1.z, v1.z, ss); ss = fmaf(v1.w, v1.w, ss);
#pragma unroll
  for (int o = 32; o; o >>= 1) ss += __shfl_xor(ss, o);
  float n = sqrtf(ss);
  if (lane == 0) *ndst = n;
  float ci = 1.0f / (n + EPSF);
  uint4 pv;
  pv.x = pk2bf(v0.x * ci, v0.y * ci);
  pv.y = pk2bf(v0.z * ci, v0.w * ci);
  pv.z = pk2bf(v1.x * ci, v1.y * ci);
  pv.w = pk2bf(v1.z * ci, v1.w * ci);
  ((uint4*)dst)[lane] = pv;
}

// ---------------------------------------------------------------------------
// Kernel 2: bf16 Gram matrices via MFMA (LDS-staged bodies), one launch.
// ---------------------------------------------------------------------------
template <int LS>
__device__ __forceinline__ void gram_body(const unsigned short* __restrict__ ctxn,
                                          unsigned short* __restrict__ Gbf,
                                          int c, char* sm) {
  constexpr int RW = (LS / 16) / 2;
  const int t = threadIdx.x;
  const int w = t >> 6, lane = t & 63, m16 = lane & 15, grp = lane >> 4;
  const int rT0 = (w & 1) * RW, cT0 = (w >> 1) * RW;
  const unsigned short* base = ctxn + ((size_t)c * LS << 9);
  f32x4 g[RW][RW];
#pragma unroll
  for (int ri = 0; ri < RW; ri++)
#pragma unroll
    for (int ci = 0; ci < RW; ci++) g[ri][ci] = {0.f, 0.f, 0.f, 0.f};

  for (int ch = 0; ch < 4; ch++) {
    __syncthreads();
    for (int idx = t; idx < LS * 16; idx += 256) {
      int row = idx >> 4, u = idx & 15;
      *(uint4*)(sm + row * 272 + u * 16) =
          ((const uint4*)(base + ((size_t)row << 9) + (ch << 7)))[u];
    }
    __syncthreads();
#pragma unroll
    for (int kk = 0; kk < 4; kk++) {
      short8 a[RW], b[RW];
#pragma unroll
      for (int ri = 0; ri < RW; ri++)
        a[ri] = *(const short8*)(sm + ((rT0 + ri) * 16 + m16) * 272 + kk * 64 + grp * 16);
#pragma unroll
      for (int ci = 0; ci < RW; ci++)
        b[ci] = *(const short8*)(sm + ((cT0 + ci) * 16 + m16) * 272 + kk * 64 + grp * 16);
#pragma unroll
      for (int ri = 0; ri < RW; ri++)
#pragma unroll
        for (int ci = 0; ci < RW; ci++)
          g[ri][ci] = __builtin_amdgcn_mfma_f32_16x16x32_bf16(a[ri], b[ci], g[ri][ci], 0, 0, 0);
    }
  }
#pragma unroll
  for (int ri = 0; ri < RW; ri++)
#pragma unroll
    for (int ci = 0; ci < RW; ci++)
#pragma unroll
      for (int r = 0; r < 4; r++) {
        int s = (rT0 + ri) * 16 + grp * 4 + r;
        int sp = (cT0 + ci) * 16 + m16;
        Gbf[(size_t)c * LS * LS + s * LS + sp] = f2bf(g[ri][ci][r]);
      }
}

__global__ __launch_bounds__(256, 2) void gram_all(
    const unsigned short* __restrict__ imn, const unsigned short* __restrict__ sn,
    unsigned short* __restrict__ Gim, unsigned short* __restrict__ Gs) {
  __shared__ __align__(16) char sm[64 * 272];
  if (blockIdx.x < 128) gram_body<64>(imn, Gim, blockIdx.x, sm);
  else gram_body<32>(sn, Gs, blockIdx.x - 128, sm);
}

// ---------------------------------------------------------------------------
// Kernel 3: PAIRED attention.
//   This round: WAVE-PRIVATE t2i pass. mp = 32*w + (lane&31), h = lane>>5:
//   each wave writes exactly the E_T rows its own MFMA reads -> all 8
//   ci-loop barriers removed (in-wave DS ordering suffices); sev cross-half
//   combine via __shfl_xor(.,32) (P scratch dropped); one barrier after the
//   loop covers cross-wave sevt/wn2t reads.
// LDS: staging 32768 | S0 33792 (aliases) + E_T/psum 8192 @36864
//    + float scratch 8224 @45056 = 53280 B -> 3 blocks/CU.
// ---------------------------------------------------------------------------
__global__ __launch_bounds__(256, 3) void attn_pair(
    const unsigned short* __restrict__ imn, const unsigned short* __restrict__ sn,
    const unsigned short* __restrict__ Gim, const unsigned short* __restrict__ Gs,
    const float* __restrict__ nim, const float* __restrict__ ns,
    const float* __restrict__ im_m, const float* __restrict__ s_m,
    float* __restrict__ i2t, float* __restrict__ t2i) {
  constexpr int S0P = 264;
  constexpr int GOFF = 36864;        // E_T (t2i) / psum (i2t P3), 8 KB
  constexpr int FOFF = GOFF + 8192;  // 45056: float scratch
  __shared__ __align__(16) char sm[FOFF + 2056 * 4];
  float* F = (float*)(sm + FOFF);
  float* rinv_i = F;          // [4][128] (persistent, pre-scaled by LAM*log2e)
  float* cmv_i = F + 512;     // [128]    (persistent; transformed in place)
  float* cmmax_i = F + 640;   // [2]+pad
  float* rinv_t = F + 644;    // [2][128] (t2i) | alias: sumev_i [2][128]
  float* sevt = F + 900;      // [4][128] raw sev (t2i)
  float* wn2t = F + 1412;     // [4][128] raw wn2 (t2i)
  float* cmv_t = F + 1924;    // [128]
  float* cmmax_t = F + 2052;  // [4]
  float* sumev_i = F + 644;
  float* psum = (float*)(sm + GOFF);  // [4][128] (i2t P3; E_T dead by then)

  const int bq = blockIdx.x;  // caption block: 4 cap ctxs = 128 cap rows
  const int bc = blockIdx.y;  // image block:   2 img ctxs = 128 img rows
  const int t = threadIdx.x;
  const int w = t >> 6, lane = t & 63, m16 = lane & 15, grp = lane >> 4;
  auto soff = [](int n) { return n * S0P; };

  const unsigned short* aBase = imn + ((size_t)bc << 16);  // img rows (ctx for i2t)
  const unsigned short* bBase = sn + ((size_t)bq << 16);   // cap rows (qry for i2t)

  // ---- preload masks, G_im fragments -> registers ----
  if (t < 128) cmv_i[t] = im_m[bc * 128 + t];
  else cmv_t[t - 128] = s_m[bq * 128 + (t - 128)];
  const int c3 = w >> 1, hf = w & 1;  // i2t P3: WPC=2
  short8 g_a[2][2];
  {
    const unsigned short* gB = Gim + ((size_t)bc * 2 + c3) * 4096;
#pragma unroll
    for (int mi = 0; mi < 2; mi++) {
      int sp = (hf * 2 + mi) * 16 + m16;
#pragma unroll
      for (int ks = 0; ks < 2; ks++)
        g_a[mi][ks] = *(const short8*)(gB + sp * 64 + ks * 32 + grp * 8);
    }
  }

  f32x4 regs[16];
#pragma unroll
  for (int i = 0; i < 16; i++) regs[i] = {0.f, 0.f, 0.f, 0.f};

  // ---- Phase 1: 128x128x512 score GEMM (global_load_lds staging) ----
  const int sT0 = (w & 1) * 4, nT0 = (w >> 1) * 4;
  const int r_lane = lane >> 3, c_lane = lane & 7;
  const unsigned short* wbase = (w < 2) ? (aBase + ((size_t)(w * 64) << 9))
                                        : (bBase + ((size_t)((w - 2) * 64) << 9));
  const unsigned short* pb = wbase + r_lane * 512 + ((c_lane ^ r_lane) << 3);
  char* ldsw = sm + w * 8192;
  const int sx = m16 & 7;
  for (int ch = 0; ch < 8; ch++) {
    __syncthreads();
#pragma unroll
    for (int j = 0; j < 8; j++)
      gload_lds16(pb + ch * 64 + j * 4096, ldsw + j * 1024);
    __syncthreads();
#pragma unroll
    for (int kk = 0; kk < 2; kk++) {
      short8 av[4], bv[4];
#pragma unroll
      for (int si = 0; si < 4; si++)
        av[si] = *(const short8*)(sm + (((sT0 + si) * 16 + m16) << 7) +
                                  (((kk * 4 + grp) ^ sx) << 4));
#pragma unroll
      for (int ni = 0; ni < 4; ni++)
        bv[ni] = *(const short8*)(sm + ((128 + (nT0 + ni) * 16 + m16) << 7) +
                                  (((kk * 4 + grp) ^ sx) << 4));
#pragma unroll
      for (int si = 0; si < 4; si++)
#pragma unroll
        for (int ni = 0; ni < 4; ni++)
          regs[si * 4 + ni] = __builtin_amdgcn_mfma_f32_16x16x32_bf16(
              av[si], bv[ni], regs[si * 4 + ni], 0, 0, 0);
    }
  }
  __syncthreads();
  // S0 bf16 [n=cap][m=img]
#pragma unroll
  for (int si = 0; si < 4; si++)
#pragma unroll
    for (int ni = 0; ni < 4; ni++) {
      int n = (nT0 + ni) * 16 + m16;
      int m0 = (sT0 + si) * 16 + grp * 4;
      f32x4 a = regs[si * 4 + ni];
      uint2 p;
      p.x = pk2bf(a[0], a[1]);
      p.y = pk2bf(a[2], a[3]);
      *(uint2*)(sm + soff(n) + m0 * 2) = p;
    }
  __syncthreads();

  // ---- rinv stage: i2t rinv (threads 0..127), t2i rinv (threads 128..255),
  //      cmmax by threads 0..5. rinv stored pre-scaled by LAM*log2e. ----
  if (t < 128) {
    if (t < 2) {
      float mx = cmv_i[t * 64];
      for (int s = 1; s < 64; s++) mx = fmaxf(mx, cmv_i[t * 64 + s]);
      cmmax_i[t] = mx;
    } else if (t < 6) {
      int ci = t - 2;
      float mx = cmv_t[ci * 32];
      for (int s = 1; s < 32; s++) mx = fmaxf(mx, cmv_t[ci * 32 + s]);
      cmmax_t[ci] = mx;
    }
    int qi = t >> 5, mg = (t & 31) * 4;
    f32x2 sa = {0.f, 0.f}, sb = {0.f, 0.f};
#pragma unroll 8
    for (int l = 0; l < 32; l++) {
      uint2 pk = *(const uint2*)(sm + soff(qi * 32 + l) + mg * 2);
      f32x2 v01 = {__uint_as_float(pk.x << 16),
                   __uint_as_float(pk.x & 0xffff0000u)};
      f32x2 v23 = {__uint_as_float(pk.y << 16),
                   __uint_as_float(pk.y & 0xffff0000u)};
      f32x2 l01 = lrelu2(v01), l23 = lrelu2(v23);
      sa = fma2(l01, l01, sa);
      sb = fma2(l23, l23, sb);
    }
    rinv_i[qi * 128 + mg + 0] = LAML2E / (sqrtf(sa.x) + EPSF);
    rinv_i[qi * 128 + mg + 1] = LAML2E / (sqrtf(sa.y) + EPSF);
    rinv_i[qi * 128 + mg + 2] = LAML2E / (sqrtf(sb.x) + EPSF);
    rinv_i[qi * 128 + mg + 3] = LAML2E / (sqrtf(sb.y) + EPSF);
  } else {
    int n = t - 128;  // cap row
#pragma unroll
    for (int qi = 0; qi < 2; qi++) {
      f32x2 ssa = {0.f, 0.f}, ssb = {0.f, 0.f};
#pragma unroll 4
      for (int j = 0; j < 16; j++) {
        uint2 pk = *(const uint2*)(sm + soff(n) + qi * 128 + j * 8);
        f32x2 v01 = {__uint_as_float(pk.x << 16),
                     __uint_as_float(pk.x & 0xffff0000u)};
        f32x2 v23 = {__uint_as_float(pk.y << 16),
                     __uint_as_float(pk.y & 0xffff0000u)};
        f32x2 l01 = lrelu2(v01), l23 = lrelu2(v23);
        ssa = fma2(l01, l01, ssa);
        ssb = fma2(l23, l23, ssb);
      }
      float ss = (ssa.x + ssa.y) + (ssb.x + ssb.y);
      rinv_t[qi * 128 + n] = LAML2E / (sqrtf(ss) + EPSF);
    }
  }
  __syncthreads();

  // ---- fold masks: cmv <- K*(cmv - 1 - cmmax), K=LAM*log2e
  //      (e = exp2(fma(l,rv,cv))) ----
  if (t < 128) cmv_i[t] = (cmv_i[t] - 1.0f - cmmax_i[t >> 6]) * LAML2E;
  else {
    int n2 = t - 128;
    cmv_t[n2] = (cmv_t[n2] - 1.0f - cmmax_t[n2 >> 5]) * LAML2E;
  }
  __syncthreads();

  // ---- t2i MFMA pass, WAVE-PRIVATE (no barriers in the ci loop):
  //      wave w owns img cols mp in [32w, 32w+32); lane&31 selects mp,
  //      lane>>5 selects s-half. E_T rows [32w,32w+32) are written and read
  //      only by wave w. Cross-half sev via __shfl_xor(.,32). ----
  {
    const int mp = 32 * w + (lane & 31);  // img col (wave-private range)
    const int h = lane >> 5;              // s-half
    const int qi = w >> 1;                // mp>>6, wave-uniform
    char* ET = sm + GOFF;
    const unsigned short* gB2 = Gs + ((size_t)bq << 12);
    const int esw = (mp >> 1) & 3;   // write-side chunk swizzle
    const int rsw = (m16 >> 1) & 3;  // read-side chunk swizzle
    for (int ci = 0; ci < 4; ci++) {
      // G_s A-fragments for this ctx (direct global loads, L1-hot after rep 0)
      short8 ga0 = *(const short8*)(gB2 + ci * 1024 + m16 * 32 + grp * 8);
      short8 ga1 = *(const short8*)(gB2 + ci * 1024 + (16 + m16) * 32 + grp * 8);
      const float* rv = rinv_t + qi * 128 + ci * 32 + h * 16;
      const float* cv = cmv_t + ci * 32 + h * 16;
      f32x2 sev2 = {0.f, 0.f};
      unsigned pk[8];
#pragma unroll
      for (int q = 0; q < 4; q++) {
        float4 r4 = *(const float4*)(rv + q * 4);
        float4 c4 = *(const float4*)(cv + q * 4);
        int s0 = ci * 32 + h * 16 + q * 4;
        float v0 = bf2f(*(const unsigned short*)(sm + soff(s0 + 0) + mp * 2));
        float v1 = bf2f(*(const unsigned short*)(sm + soff(s0 + 1) + mp * 2));
        float v2 = bf2f(*(const unsigned short*)(sm + soff(s0 + 2) + mp * 2));
        float v3 = bf2f(*(const unsigned short*)(sm + soff(s0 + 3) + mp * 2));
        f32x2 v01 = {v0, v1}, v23 = {v2, v3};
        f32x2 a01 = fma2(lrelu2(v01), (f32x2){r4.x, r4.y}, (f32x2){c4.x, c4.y});
        f32x2 a23 = fma2(lrelu2(v23), (f32x2){r4.z, r4.w}, (f32x2){c4.z, c4.w});
        float e0 = exp2v(a01.x), e1 = exp2v(a01.y);
        float e2 = exp2v(a23.x), e3 = exp2v(a23.y);
        sev2 = fma2((f32x2){e0, e1}, v01, sev2);
        sev2 = fma2((f32x2){e2, e3}, v23, sev2);
        pk[q * 2] = pk2bf_t(e0, e1);
        pk[q * 2 + 1] = pk2bf_t(e2, e3);
      }
      // cross-half sev combine (same mp lives in lanes l and l+32)
      float sp_ = sev2.x + sev2.y;
      float sfull = sp_ + __shfl_xor(sp_, 32);
      if (h == 0) sevt[ci * 128 + mp] = sfull;  // order: h0 + h1 (== old)
      uint4 w0; w0.x = pk[0]; w0.y = pk[1]; w0.z = pk[2]; w0.w = pk[3];
      uint4 w1; w1.x = pk[4]; w1.y = pk[5]; w1.z = pk[6]; w1.w = pk[7];
      char* rowp = ET + mp * 64;
      *(uint4*)(rowp + (((2 * h) ^ esw) << 4)) = w0;
      *(uint4*)(rowp + (((2 * h + 1) ^ esw) << 4)) = w1;
      // MFMA: wave w owns n-tiles {2w, 2w+1} == E_T rows it just wrote
      short8 bfrag[2];
#pragma unroll
      for (int nt = 0; nt < 2; nt++)
        bfrag[nt] = *(const short8*)(ET + (((w * 2 + nt) * 16 + m16) << 6) +
                                     ((grp ^ rsw) << 4));
      f32x4 u00 = __builtin_amdgcn_mfma_f32_16x16x32_bf16(ga0, bfrag[0], (f32x4){0.f, 0.f, 0.f, 0.f}, 0, 0, 0);
      f32x4 u01 = __builtin_amdgcn_mfma_f32_16x16x32_bf16(ga0, bfrag[1], (f32x4){0.f, 0.f, 0.f, 0.f}, 0, 0, 0);
      f32x4 u10 = __builtin_amdgcn_mfma_f32_16x16x32_bf16(ga1, bfrag[0], (f32x4){0.f, 0.f, 0.f, 0.f}, 0, 0, 0);
      f32x4 u11 = __builtin_amdgcn_mfma_f32_16x16x32_bf16(ga1, bfrag[1], (f32x4){0.f, 0.f, 0.f, 0.f}, 0, 0, 0);
#pragma unroll
      for (int nt = 0; nt < 2; nt++) {
        const char* erow = ET + (((w * 2 + nt) * 16 + m16) << 6);
        float part = 0.f;
#pragma unroll
        for (int mt = 0; mt < 2; mt++) {
          int cch = 2 * mt + (grp >> 1);
          uint2 ee = *(const uint2*)(erow + ((cch ^ rsw) << 4) + ((grp & 1) << 3));
          f32x4 uu = (mt == 0) ? (nt == 0 ? u00 : u01) : (nt == 0 ? u10 : u11);
          part += __uint_as_float(ee.x << 16) * uu[0];
          part += __uint_as_float(ee.x & 0xffff0000u) * uu[1];
          part += __uint_as_float(ee.y << 16) * uu[2];
          part += __uint_as_float(ee.y & 0xffff0000u) * uu[3];
        }
        part += __shfl_xor(part, 16);
        part += __shfl_xor(part, 32);
        if (lane < 16) wn2t[ci * 128 + (w * 2 + nt) * 16 + m16] = part;
      }
    }
  }
  __syncthreads();  // cross-wave: sevt/wn2t complete before t2i final

  // ---- t2i final: cos + mean over 64 img words (inv-cancelled form) ----
  {
    const int p = t >> 5, l0 = t & 31;
    const int cc = p >> 1, qi = p & 1;
    float sum = 0.f;
#pragma unroll
    for (int li = 0; li < 2; li++) {
      int n = qi * 64 + l0 + li * 32;
      float nq = nim[bc * 128 + n];
      float sev = sevt[cc * 128 + n];
      float wn2 = wn2t[cc * 128 + n];
      float denom = fmaxf(nq * sqrtf(fmaxf(wn2, 0.f)), 1e-30f);
      sum += (nq + EPSF) * sev / denom;
    }
#pragma unroll
    for (int o = 1; o < 32; o <<= 1) sum += __shfl_xor(sum, o);
    if (l0 == 0) t2i[(bq * 4 + cc) * 128 + bc * 2 + qi] = sum * (1.0f / 64.f);
  }
  __syncthreads();  // rinv_t region dies; sumev_i aliases it

  // ---- i2t 2b: one-pass e in place (sum/inv dropped — cancels in final) ----
  {
    const int n = t & 127;
    const int qi = n >> 5;
    const int ci = t >> 7;  // GC=2, one ci per thread
    char* rowp = sm + soff(n) + ci * 128;
    const float* rv = rinv_i + qi * 128 + ci * 64;
    const float* cv = cmv_i + ci * 64;
    f32x2 sev2 = {0.f, 0.f};
#pragma unroll
    for (int u = 0; u < 16; u++) {
      uint2 pk = *(const uint2*)(rowp + u * 8);
      float4 rv4 = *(const float4*)(rv + u * 4);
      float4 cv4 = *(const float4*)(cv + u * 4);
      f32x2 v01 = {__uint_as_float(pk.x << 16),
                   __uint_as_float(pk.x & 0xffff0000u)};
      f32x2 v23 = {__uint_as_float(pk.y << 16),
                   __uint_as_float(pk.y & 0xffff0000u)};
      f32x2 a01 = fma2(lrelu2(v01), (f32x2){rv4.x, rv4.y}, (f32x2){cv4.x, cv4.y});
      f32x2 a23 = fma2(lrelu2(v23), (f32x2){rv4.z, rv4.w}, (f32x2){cv4.z, cv4.w});
      float e0 = exp2v(a01.x), e1 = exp2v(a01.y);
      float e2 = exp2v(a23.x), e3 = exp2v(a23.y);
      sev2 = fma2((f32x2){e0, e1}, v01, sev2);
      sev2 = fma2((f32x2){e2, e3}, v23, sev2);
      uint2 o;
      o.x = pk2bf_t(e0, e1);
      o.y = pk2bf_t(e2, e3);
      *(uint2*)(rowp + u * 8) = o;
    }
    sumev_i[ci * 128 + n] = sev2.x + sev2.y;
  }
  __syncthreads();

  // ---- i2t P3: U = G_im @ e (MFMA, A from regs); wn2 from C-regs ----
  {
#pragma unroll
    for (int i = 0; i < 16; i++) regs[i] = {0.f, 0.f, 0.f, 0.f};
#pragma unroll
    for (int ks = 0; ks < 2; ks++) {
      short8 b2[8];
#pragma unroll
      for (int nt = 0; nt < 8; nt++) {
        const char* p = sm + soff(nt * 16 + m16) + c3 * 128 + ks * 64 + grp * 16;
        union { uint2 h[2]; short8 v; } bb;
        bb.h[0] = *(const uint2*)(p);
        bb.h[1] = *(const uint2*)(p + 8);
        b2[nt] = bb.v;
      }
#pragma unroll
      for (int mi = 0; mi < 2; mi++)
#pragma unroll
        for (int nt = 0; nt < 8; nt++)
          regs[mi * 8 + nt] = __builtin_amdgcn_mfma_f32_16x16x32_bf16(
              g_a[mi][ks], b2[nt], regs[mi * 8 + nt], 0, 0, 0);
    }
    float wp[8];
#pragma unroll
    for (int nt = 0; nt < 8; nt++) wp[nt] = 0.f;
#pragma unroll
    for (int nt = 0; nt < 8; nt++) {
#pragma unroll
      for (int mi = 0; mi < 2; mi++) {
        int sp = (hf * 2 + mi) * 16 + grp * 4;
        uint2 ee = *(const uint2*)(sm + soff(nt * 16 + m16) + (c3 * 64 + sp) * 2);
        f32x4 uu = regs[mi * 8 + nt];
        wp[nt] += __uint_as_float(ee.x << 16) * uu[0] +
                  __uint_as_float(ee.x & 0xffff0000u) * uu[1] +
                  __uint_as_float(ee.y << 16) * uu[2] +
                  __uint_as_float(ee.y & 0xffff0000u) * uu[3];
      }
    }
#pragma unroll
    for (int o = 16; o < 64; o <<= 1)
#pragma unroll
      for (int nt = 0; nt < 8; nt++) wp[nt] += __shfl_xor(wp[nt], o);
    if (lane < 16) {
#pragma unroll
      for (int nt = 0; nt < 8; nt++) psum[w * 128 + nt * 16 + lane] = wp[nt];
    }
  }
  __syncthreads();

  // ---- i2t final: cos + mean over 32 cap words (inv-cancelled form) ----
  {
    const int p = t >> 5, l0 = t & 31;
    const int cc = p >> 2, qi = p & 3;
    int n = qi * 32 + l0;
    float nq = ns[bq * 128 + n];
    float sev = sumev_i[cc * 128 + n];
    float wn2u = psum[(cc * 2 + 0) * 128 + n] + psum[(cc * 2 + 1) * 128 + n];
    float denom = fmaxf(nq * sqrtf(fmaxf(wn2u, 0.f)), 1e-30f);
    float sum = (nq + EPSF) * sev / denom;
#pragma unroll
    for (int o = 1; o < 32; o <<= 1) sum += __shfl_xor(sum, o);
    if (l0 == 0) i2t[(bc * 2 + cc) * 128 + bq * 4 + qi] = sum * (1.0f / 32.f);
  }
}

// ---------------------------------------------------------------------------
// Kernel 4: fused loss (R11-proven).
// ---------------------------------------------------------------------------
__global__ __launch_bounds__(128) void loss_fused(
    const float* __restrict__ gsim, const float* __restrict__ i2t,
    const float* __restrict__ t2i, float* __restrict__ acc,
    float* __restrict__ out) {
  const int i = blockIdx.x, j = threadIdx.x;
  const int B = 128;
  __shared__ float sh[2];
  auto bmax = [&](float v) -> float {
#pragma unroll
    for (int o = 32; o; o >>= 1) v = fmaxf(v, __shfl_down(v, o));
    if ((j & 63) == 0) sh[j >> 6] = v;
    __syncthreads();
    float r = fmaxf(sh[0], sh[1]);
    __syncthreads();
    return r;
  };
  auto bsum = [&](float v) -> float {
#pragma unroll
    for (int o = 32; o; o >>= 1) v += __shfl_down(v, o);
    if ((j & 63) == 0) sh[j >> 6] = v;
    __syncthreads();
    float r = sh[0] + sh[1];
    __syncthreads();
    return r;
  };
  float xr = gsim[i * B + j] * 20.f;
  float xc = gsim[j * B + i] * 20.f;
  float sc = (i2t[i * B + j] + t2i[j * B + i]) * LAM;
  float mr = bmax(xr);
  float lser = mr + logf(bsum(__expf(xr - mr)));
  float mc = bmax(xc);
  float lsec = mc + logf(bsum(__expf(xc - mc)));
  float ml = bmax(sc);
  float lsel = ml + logf(bsum(__expf(sc - ml)));
  float pred = __expf(sc - lsel);
  float logLab = (i == j) ? logf(1.0f + 1e-6f) : logf(1e-6f);
  float tsum = bsum(pred * (sc - lsel - logLab));
  if (j == 0) {
    float d = gsim[i * B + i] * 20.f;
    atomicAdd(&acc[0], d - lser);
    atomicAdd(&acc[1], d - lsec);
    atomicAdd(&acc[2], tsum);
    __threadfence();
    unsigned old = atomicAdd((unsigned*)&acc[3], 1u);
    if (old == 127u) {
      __threadfence();
      float a = acc[0], b = acc[1], c = acc[2];
      float gl = -(a / 128.f) - (b / 128.f);
      float ll = c / 128.f;
      out[0] = gl + ll;
      out[1] = gl;
      out[2] = ll;
    }
  }
}

extern "C" void kernel_launch(void* const* d_in, const int* in_sizes, int n_in,
                              void* d_out, int out_size, void* d_ws,
                              size_t ws_size, hipStream_t stream) {
  const float* gsim = (const float*)d_in[0];  // (128,128)
  const float* im = (const float*)d_in[1];    // (128,64,512)
  const float* s = (const float*)d_in[2];     // (128,32,512)
  const float* im_m = (const float*)d_in[3];  // (128,64)
  const float* s_m = (const float*)d_in[5];   // (128,32)
  float* out = (float*)d_out;

  float* ws = (float*)d_ws;
  float* nim = ws;                                         // 8192
  float* ns = ws + 8192;                                   // 4096
  float* i2t = ws + 12288;                                 // 16384
  float* t2i = ws + 28672;                                 // 16384
  float* acc = ws + 45056;                                 // 4
  unsigned short* Gim = (unsigned short*)(ws + 45440);     // 128*64*64 bf16
  unsigned short* Gs = (unsigned short*)(ws + 307584);     // 128*32*32 bf16
  unsigned short* imn = (unsigned short*)(ws + 373120);    // 128*64*512 bf16
  unsigned short* sn = (unsigned short*)(ws + 2470272);    // 128*32*512 bf16

  norm_convert<<<dim3(3072), dim3(256), 0, stream>>>(im, s, nim, ns, imn, sn, acc);
  gram_all<<<dim3(256), dim3(256), 0, stream>>>(imn, sn, Gim, Gs);
  attn_pair<<<dim3(32, 64), dim3(256), 0, stream>>>(imn, sn, Gim, Gs, nim, ns,
                                                    im_m, s_m, i2t, t2i);
  loss_fused<<<dim3(128), dim3(128), 0, stream>>>(gsim, i2t, t2i, acc, out);
}